// Round 1
// baseline (363.248 us; speedup 1.0000x reference)
//
#include <hip/hip_runtime.h>
#include <hip/hip_bf16.h>
#include <stdint.h>

// ---- problem constants ----
#define BB 64
#define NN 320
#define CC 768
#define HH 12
#define DH 64
#define NC3 2304
#define MROWS (BB*NN)   // 20480

typedef __attribute__((ext_vector_type(8))) short short8;
typedef __attribute__((ext_vector_type(4))) float f32x4;
typedef __attribute__((ext_vector_type(8))) __bf16 bf16x8;

union BF8U { short8 s; bf16x8 b; };
static __device__ __forceinline__ bf16x8 asbf(short8 v){ BF8U u; u.s = v; return u.b; }

#define MFMA16(a,b,c) __builtin_amdgcn_mfma_f32_16x16x32_bf16((a),(b),(c),0,0,0)

// ------------------------------------------------------------------
// Kernel 0: convert + transpose weights fp32 -> bf16
//   wqkvT[n][k] = bf16(W_qkv[k][n])   (2304 x 768)
//   wprojT[n][k] = bf16(W_proj[k][n]) (768 x 768)
// ------------------------------------------------------------------
__global__ __launch_bounds__(256) void convert_w(
    const float* __restrict__ Wqkv, const float* __restrict__ Wproj,
    __hip_bfloat16* __restrict__ wqkvT, __hip_bfloat16* __restrict__ wprojT)
{
  int idx = blockIdx.x * 256 + threadIdx.x;
  const int tq = NC3 * CC;            // 1769472
  if (idx < tq){
    int k = idx % CC, n = idx / CC;
    wqkvT[idx] = __float2bfloat16(Wqkv[k * NC3 + n]);
  } else {
    int j = idx - tq;                 // < 768*768 by grid sizing
    int k = j % CC, n = j / CC;
    wprojT[j] = __float2bfloat16(Wproj[k * CC + n]);
  }
}

// ------------------------------------------------------------------
// Kernel 1: qkv GEMM  (M=20480, K=768, N=2304), A fp32 on the fly -> bf16
//   epilogue scatters to q[B,H,N,Dh], k[B,H,N,Dh], vT[B,H,Dh,N] (bf16)
// ------------------------------------------------------------------
#define BM 128
#define BN 128
#define BK 64
#define LDK 72   // +8 bf16 pad: row stride 144B -> 2-way bank alias (free)

__global__ __launch_bounds__(256) void gemm_qkv(
    const float* __restrict__ X,                 // [20480][768]
    const __hip_bfloat16* __restrict__ WT,       // [2304][768]
    __hip_bfloat16* __restrict__ qb,
    __hip_bfloat16* __restrict__ kb,
    __hip_bfloat16* __restrict__ vt)
{
  __shared__ __hip_bfloat16 As[BM][LDK];
  __shared__ __hip_bfloat16 Bs[BN][LDK];
  const int tid = threadIdx.x;
  const int bm = blockIdx.x * BM;
  const int bn = blockIdx.y * BN;
  const int w = tid >> 6, lane = tid & 63;
  const int wr = w >> 1, wc = w & 1;
  const int l16 = lane & 15, lq = lane >> 4;

  f32x4 acc[4][4];
  #pragma unroll
  for (int i = 0; i < 4; ++i)
    #pragma unroll
    for (int j = 0; j < 4; ++j) acc[i][j] = (f32x4){0.f,0.f,0.f,0.f};

  for (int k0 = 0; k0 < CC; k0 += BK){
    __syncthreads();
    // stage A: 128x64 fp32 -> bf16 (8 iters x 256 thr x 4 elems)
    #pragma unroll
    for (int it = 0; it < 8; ++it){
      int linear = it * 1024 + tid * 4;
      int row = linear >> 6, kk = linear & 63;
      const float4 xv = *reinterpret_cast<const float4*>(&X[(size_t)(bm + row) * CC + k0 + kk]);
      __hip_bfloat16 tmp[4] = {__float2bfloat16(xv.x), __float2bfloat16(xv.y),
                               __float2bfloat16(xv.z), __float2bfloat16(xv.w)};
      *reinterpret_cast<uint64_t*>(&As[row][kk]) = *reinterpret_cast<const uint64_t*>(tmp);
    }
    // stage B: 128x64 bf16 (4 iters x 256 thr x 8 elems)
    #pragma unroll
    for (int it = 0; it < 4; ++it){
      int linear = it * 2048 + tid * 8;
      int row = linear >> 6, kk = linear & 63;
      short8 v = *reinterpret_cast<const short8*>(&WT[(size_t)(bn + row) * CC + k0 + kk]);
      *reinterpret_cast<short8*>(&Bs[row][kk]) = v;
    }
    __syncthreads();
    #pragma unroll
    for (int kc = 0; kc < 2; ++kc){
      short8 af[4], bfr[4];
      #pragma unroll
      for (int mi = 0; mi < 4; ++mi)
        af[mi] = *reinterpret_cast<const short8*>(&As[wr*64 + mi*16 + l16][kc*32 + lq*8]);
      #pragma unroll
      for (int ni = 0; ni < 4; ++ni)
        bfr[ni] = *reinterpret_cast<const short8*>(&Bs[wc*64 + ni*16 + l16][kc*32 + lq*8]);
      #pragma unroll
      for (int mi = 0; mi < 4; ++mi)
        #pragma unroll
        for (int ni = 0; ni < 4; ++ni)
          acc[mi][ni] = MFMA16(asbf(af[mi]), asbf(bfr[ni]), acc[mi][ni]);
    }
  }

  // epilogue: scatter bf16 to q / k / vT
  #pragma unroll
  for (int mi = 0; mi < 4; ++mi){
    #pragma unroll
    for (int ni = 0; ni < 4; ++ni){
      #pragma unroll
      for (int r = 0; r < 4; ++r){
        int row = bm + wr*64 + mi*16 + lq*4 + r;   // token index in [0,20480)
        int col = bn + wc*64 + ni*16 + l16;        // qkv col in [0,2304)
        float val = acc[mi][ni][r];
        int b = row / NN, n = row % NN;
        int s = col / CC, rem = col % CC;
        int h = rem >> 6, dh = rem & 63;
        int bh = b * HH + h;
        __hip_bfloat16 bv = __float2bfloat16(val);
        if (s == 0)      qb[((size_t)bh * NN + n) * DH + dh] = bv;
        else if (s == 1) kb[((size_t)bh * NN + n) * DH + dh] = bv;
        else             vt[((size_t)bh * DH + dh) * NN + n] = bv;
      }
    }
  }
}

// ------------------------------------------------------------------
// Kernel 2: attention. One block = (b,h) x 64 query rows; 4 waves x 16 rows.
// NKT = number of 16-key tiles: 4 (mt part) or 20 (s part).
// ------------------------------------------------------------------
template<int NKT>
__global__ __launch_bounds__(256) void attn_kernel(
    const __hip_bfloat16* __restrict__ qb,
    const __hip_bfloat16* __restrict__ kb,
    const __hip_bfloat16* __restrict__ vt,
    __hip_bfloat16* __restrict__ ob)
{
  constexpr int KV   = NKT * 16;
  constexpr int PSTR = KV + 8;           // pad -> 2-way bank alias (free)
  __shared__ __hip_bfloat16 P[4][16][PSTR];

  const int tid = threadIdx.x;
  const int w = tid >> 6, lane = tid & 63;
  const int l16 = lane & 15, lq = lane >> 4;

  int bh, qbase;
  if (NKT == 4){ bh = blockIdx.x;      qbase = 0; }
  else         { bh = blockIdx.x >> 2; qbase = 64 + (blockIdx.x & 3) * 64; }
  const int qrow0 = qbase + w * 16;

  const __hip_bfloat16* qp = qb + ((size_t)bh * NN + qrow0) * DH;
  const __hip_bfloat16* kp = kb + (size_t)bh * NN * DH;
  const __hip_bfloat16* vp = vt + (size_t)bh * DH * NN;

  // Q fragments (held for whole kernel)
  short8 aq[2];
  #pragma unroll
  for (int kc = 0; kc < 2; ++kc)
    aq[kc] = *reinterpret_cast<const short8*>(&qp[l16 * DH + kc*32 + lq*8]);

  // S = Q K^T : s[kt][r] = S[lq*4+r][kt*16+l16]
  f32x4 s[NKT];
  #pragma unroll
  for (int kt = 0; kt < NKT; ++kt){
    f32x4 a = (f32x4){0.f,0.f,0.f,0.f};
    #pragma unroll
    for (int kc = 0; kc < 2; ++kc){
      short8 bk = *reinterpret_cast<const short8*>(&kp[(kt*16 + l16) * DH + kc*32 + lq*8]);
      a = MFMA16(asbf(aq[kc]), asbf(bk), a);
    }
    s[kt] = a;
  }

  // softmax over KV cols (rows lq*4+r); logits = s * 0.125
  const float scale = 0.125f;
  float sum[4];
  #pragma unroll
  for (int r = 0; r < 4; ++r){
    float mx = -1e30f;
    #pragma unroll
    for (int kt = 0; kt < NKT; ++kt) mx = fmaxf(mx, s[kt][r]);
    #pragma unroll
    for (int off = 1; off < 16; off <<= 1) mx = fmaxf(mx, __shfl_xor(mx, off));
    float sm = 0.f;
    #pragma unroll
    for (int kt = 0; kt < NKT; ++kt){
      float p = __expf((s[kt][r] - mx) * scale);
      __hip_bfloat16 pb = __float2bfloat16(p);
      P[w][lq*4 + r][kt*16 + l16] = pb;
      sm += __bfloat162float(pb);       // denominator consistent with bf16 P
    }
    #pragma unroll
    for (int off = 1; off < 16; off <<= 1) sm += __shfl_xor(sm, off);
    sum[r] = sm;
  }
  __syncthreads();   // drain LDS writes before cross-lane fragment reads

  // O = P V : per dh-tile nt, o[nt][r] = O[lq*4+r][nt*16+l16]
  f32x4 o[4];
  #pragma unroll
  for (int nt = 0; nt < 4; ++nt) o[nt] = (f32x4){0.f,0.f,0.f,0.f};
  #pragma unroll
  for (int kc = 0; kc < KV/32; ++kc){
    short8 ap = *reinterpret_cast<const short8*>(&P[w][l16][kc*32 + lq*8]);
    #pragma unroll
    for (int nt = 0; nt < 4; ++nt){
      short8 bv = *reinterpret_cast<const short8*>(&vp[(nt*16 + l16) * NN + kc*32 + lq*8]);
      o[nt] = MFMA16(asbf(ap), asbf(bv), o[nt]);
    }
  }

  // write o / sum -> ob[b*320 + qrow][h*64 + dh]
  const int b = bh / HH, h = bh % HH;
  #pragma unroll
  for (int nt = 0; nt < 4; ++nt){
    #pragma unroll
    for (int r = 0; r < 4; ++r){
      int qrow = qrow0 + lq*4 + r;
      int dh = nt*16 + l16;
      float val = o[nt][r] / sum[r];
      ob[((size_t)b * NN + qrow) * CC + h * DH + dh] = __float2bfloat16(val);
    }
  }
}

// ------------------------------------------------------------------
// Kernel 3: proj GEMM (M=20480, K=768, N=768) + bias, fp32 out
// ------------------------------------------------------------------
__global__ __launch_bounds__(256) void gemm_proj(
    const __hip_bfloat16* __restrict__ A,        // [20480][768] bf16
    const __hip_bfloat16* __restrict__ WT,       // [768][768] bf16 (transposed)
    const float* __restrict__ bias,
    float* __restrict__ out)
{
  __shared__ __hip_bfloat16 As[BM][LDK];
  __shared__ __hip_bfloat16 Bs[BN][LDK];
  const int tid = threadIdx.x;
  const int bm = blockIdx.x * BM;
  const int bn = blockIdx.y * BN;
  const int w = tid >> 6, lane = tid & 63;
  const int wr = w >> 1, wc = w & 1;
  const int l16 = lane & 15, lq = lane >> 4;

  f32x4 acc[4][4];
  #pragma unroll
  for (int i = 0; i < 4; ++i)
    #pragma unroll
    for (int j = 0; j < 4; ++j) acc[i][j] = (f32x4){0.f,0.f,0.f,0.f};

  for (int k0 = 0; k0 < CC; k0 += BK){
    __syncthreads();
    #pragma unroll
    for (int it = 0; it < 4; ++it){
      int linear = it * 2048 + tid * 8;
      int row = linear >> 6, kk = linear & 63;
      short8 v = *reinterpret_cast<const short8*>(&A[(size_t)(bm + row) * CC + k0 + kk]);
      *reinterpret_cast<short8*>(&As[row][kk]) = v;
    }
    #pragma unroll
    for (int it = 0; it < 4; ++it){
      int linear = it * 2048 + tid * 8;
      int row = linear >> 6, kk = linear & 63;
      short8 v = *reinterpret_cast<const short8*>(&WT[(size_t)(bn + row) * CC + k0 + kk]);
      *reinterpret_cast<short8*>(&Bs[row][kk]) = v;
    }
    __syncthreads();
    #pragma unroll
    for (int kc = 0; kc < 2; ++kc){
      short8 af[4], bfr[4];
      #pragma unroll
      for (int mi = 0; mi < 4; ++mi)
        af[mi] = *reinterpret_cast<const short8*>(&As[wr*64 + mi*16 + l16][kc*32 + lq*8]);
      #pragma unroll
      for (int ni = 0; ni < 4; ++ni)
        bfr[ni] = *reinterpret_cast<const short8*>(&Bs[wc*64 + ni*16 + l16][kc*32 + lq*8]);
      #pragma unroll
      for (int mi = 0; mi < 4; ++mi)
        #pragma unroll
        for (int ni = 0; ni < 4; ++ni)
          acc[mi][ni] = MFMA16(asbf(af[mi]), asbf(bfr[ni]), acc[mi][ni]);
    }
  }

  #pragma unroll
  for (int mi = 0; mi < 4; ++mi){
    #pragma unroll
    for (int ni = 0; ni < 4; ++ni){
      #pragma unroll
      for (int r = 0; r < 4; ++r){
        int row = bm + wr*64 + mi*16 + lq*4 + r;
        int col = bn + wc*64 + ni*16 + l16;
        out[(size_t)row * CC + col] = acc[mi][ni][r] + bias[col];
      }
    }
  }
}

// ------------------------------------------------------------------
extern "C" void kernel_launch(void* const* d_in, const int* in_sizes, int n_in,
                              void* d_out, int out_size, void* d_ws, size_t ws_size,
                              hipStream_t stream)
{
  const float* x     = (const float*)d_in[0];
  const float* Wqkv  = (const float*)d_in[1];
  const float* Wproj = (const float*)d_in[2];
  const float* bproj = (const float*)d_in[3];
  float* out = (float*)d_out;

  char* ws = (char*)d_ws;
  __hip_bfloat16* wqkvT  = (__hip_bfloat16*)ws; ws += (size_t)NC3 * CC * 2;      // 3.54 MB
  __hip_bfloat16* wprojT = (__hip_bfloat16*)ws; ws += (size_t)CC * CC * 2;       // 1.18 MB
  const size_t headsz = (size_t)BB * HH * NN * DH * 2;                           // 31.46 MB
  __hip_bfloat16* qb = (__hip_bfloat16*)ws; ws += headsz;
  __hip_bfloat16* kb = (__hip_bfloat16*)ws; ws += headsz;
  __hip_bfloat16* vt = (__hip_bfloat16*)ws; ws += headsz;
  __hip_bfloat16* ob = (__hip_bfloat16*)ws; ws += headsz;

  // 0) weights -> bf16 transposed
  convert_w<<<(NC3*CC + CC*CC) / 256, 256, 0, stream>>>(Wqkv, Wproj, wqkvT, wprojT);
  // 1) qkv GEMM + scatter
  gemm_qkv<<<dim3(MROWS / BM, NC3 / BN), 256, 0, stream>>>(x, wqkvT, qb, kb, vt);
  // 2) attention: mt (q 0..63, kv 64) and s (q 64..319, kv 320)
  attn_kernel<4><<<BB * HH, 256, 0, stream>>>(qb, kb, vt, ob);
  attn_kernel<20><<<BB * HH * 4, 256, 0, stream>>>(qb, kb, vt, ob);
  // 3) proj GEMM + bias
  gemm_proj<<<dim3(MROWS / BM, CC / BN), 256, 0, stream>>>(ob, wprojT, bproj, out);
}